// Round 7
// baseline (14.196 us; speedup 1.0000x reference)
//
#include <hip/hip_runtime.h>

#define RWIN 5
#define TMAX 8192
#define NROW 2048

// Kernel 1: one wave per (row, window) task; 512-thread blocks = 8 tasks.
// Fine tasks (max ~6.6 KB) shrink the greedy-dispatch makespan tail vs
// whole-row tasks (max 32 KB). Each wave pre-issues its <=7 independent
// float4 loads (one waitcnt), masks only the 2 edge iterations, reduces via
// a 64-lane butterfly, and writes {max,min} to ws. No LDS, no barriers,
// no atomics.
__global__ __launch_bounds__(512) void window_minmax_kernel(
    const float* __restrict__ in, const int* __restrict__ lengths,
    float* __restrict__ ws)
{
    const int tid  = threadIdx.x;
    const int lane = tid & 63;
    const int task = blockIdx.x * 8 + (tid >> 6);   // 0..10239
    const int row  = task & (NROW - 1);
    const int win  = task >> 11;                    // 0..4

    const int L = lengths[row];
    const float* rowp = in + (size_t)row * TMAX;
    const int s  = (win * L) / RWIN;                     // start (incl)
    const int e  = ((win + 1) * L + (RWIN - 1)) / RWIN;  // end (excl), >= s+1
    const int sa = s & ~3;                               // aligned start
    const int niter = (e - sa + 255) >> 8;               // 1..7 iters of 256

    const float NINF = -__builtin_inff();
    const float PINF =  __builtin_inff();
    const int t0 = sa + lane * 4;

    // Pre-issue all loads back-to-back (tail lanes clamp to sa: aligned, in-row).
    float4 v[7];
    #pragma unroll
    for (int i = 0; i < 7; ++i) {
        if (i < niter) {
            const int t = t0 + (i << 8);
            v[i] = *reinterpret_cast<const float4*>(rowp + (t < e ? t : sa));
        }
    }

    // Reduce: interior iterations fully inside [s,e); edges masked per element.
    float mx = NINF, mn = PINF;
    #pragma unroll
    for (int i = 0; i < 7; ++i) {
        if (i < niter) {
            if (i > 0 && i < niter - 1) {
                mx = fmaxf(mx, fmaxf(fmaxf(v[i].x, v[i].y), fmaxf(v[i].z, v[i].w)));
                mn = fminf(mn, fminf(fminf(v[i].x, v[i].y), fminf(v[i].z, v[i].w)));
            } else {
                const int t = t0 + (i << 8);
                const float xs[4] = {v[i].x, v[i].y, v[i].z, v[i].w};
                #pragma unroll
                for (int j = 0; j < 4; ++j) {
                    const int  idx = t + j;
                    const bool ok  = (idx >= s) & (idx < e);
                    mx = fmaxf(mx, ok ? xs[j] : NINF);
                    mn = fminf(mn, ok ? xs[j] : PINF);
                }
            }
        }
    }

    #pragma unroll
    for (int off = 1; off < 64; off <<= 1) {
        mx = fmaxf(mx, __shfl_xor(mx, off));
        mn = fminf(mn, __shfl_xor(mn, off));
    }
    if (lane == 0) {
        ws[row * (2 * RWIN) + win]        = mx;
        ws[row * (2 * RWIN) + RWIN + win] = mn;
    }
}

// Kernel 2: one thread per output value; 10-element rank sort (stable by index).
__global__ __launch_bounds__(256) void rank_sort_kernel(
    const float* __restrict__ ws, float* __restrict__ out, int n)
{
    const int g = blockIdx.x * 256 + threadIdx.x;
    if (g >= n) return;
    const int row = g / (2 * RWIN);
    const int j   = g % (2 * RWIN);
    const float* base = ws + row * (2 * RWIN);
    const float v = base[j];
    int pos = 0;
    #pragma unroll
    for (int k = 0; k < 2 * RWIN; ++k) {
        const float vk = base[k];
        pos += (int)((vk < v) | ((vk == v) & (k < j)));
    }
    out[row * (2 * RWIN) + pos] = v;
}

extern "C" void kernel_launch(void* const* d_in, const int* in_sizes, int n_in,
                              void* d_out, int out_size, void* d_ws, size_t ws_size,
                              hipStream_t stream) {
    const float* in      = (const float*)d_in[0];
    const int*   lengths = (const int*)d_in[1];
    float*       out     = (float*)d_out;
    float*       ws      = (float*)d_ws;     // NROW*10 floats

    const int ntask = NROW * RWIN;           // 10240
    window_minmax_kernel<<<ntask / 8, 512, 0, stream>>>(in, lengths, ws);

    const int n = NROW * 2 * RWIN;
    rank_sort_kernel<<<(n + 255) / 256, 256, 0, stream>>>(ws, out, n);
}